// Round 4
// baseline (564.150 us; speedup 1.0000x reference)
//
#include <hip/hip_runtime.h>
#include <cstdint>

#define LYR 2
#define DM  256
#define DFFN 1024
#define CINC 512
#define BBATCH 8
#define HWTOT 4096
#define EPSV 1e-5f

using u16 = unsigned short;
typedef __attribute__((ext_vector_type(8))) short bf16x8;
typedef __attribute__((ext_vector_type(4))) float f32x4;

__device__ inline u16 f2b(float v) {
    union { float f; uint32_t u; } x; x.f = v;
    uint32_t r = x.u + 0x7fffu + ((x.u >> 16) & 1u);
    return (u16)(r >> 16);
}
__device__ inline uint32_t pk2(float a, float b) {
    return (uint32_t)f2b(a) | ((uint32_t)f2b(b) << 16);
}
__device__ inline float blo(uint32_t d) {
    union { uint32_t i; float f; } x; x.i = d << 16; return x.f;
}
__device__ inline float bhi(uint32_t d) {
    union { uint32_t i; float f; } x; x.i = d & 0xffff0000u; return x.f;
}

// ============ bf16 MFMA GEMM: C = A(M,K) @ Bt(N,K)^T, 128x128 tile, BK=64 ============
// Swapped-operand mfma: lane holds 4 consecutive output COLUMNS -> packed stores.
// MODE 0: bf16 out, x+shift[col]                   (val)
// MODE 1: bf16 out, relu(x*scale[col]+shift[col])  (proj_in)
// MODE 2: fp32 out, x+shift[col]                   (offattn, Wo, FFN2)
// MODE 3: fp32 out, relu(x*scale[row]+shift[row])  (proj_out)
// MODE 4: bf16 out, relu(x+shift[col])             (FFN1)
template<int MODE>
__global__ __launch_bounds__(256) void mfma_gemm(
    const u16* __restrict__ A, const u16* __restrict__ Bt,
    const float* __restrict__ scale, const float* __restrict__ shift,
    void* __restrict__ Cv, int M, int N, int K, int ldc,
    long long a_zs, long long b_zs, long long c_zs, int swz, int gxlog)
{
    __shared__ u16 As[8192];   // 128 rows x 64 (8 chunks of 8 u16, xor-swizzled)
    __shared__ u16 Bs[8192];
    const int tid = threadIdx.x;
    const int lane = tid & 63;
    const int wid = tid >> 6;
    const int wm = (wid & 1) << 6, wn = (wid >> 1) << 6;
    const int quad = lane >> 4, r = lane & 15;

    int bx = blockIdx.x, by = blockIdx.y;
    if (swz) {  // XCD-band swizzle: XCD k owns a contiguous band of row-tiles
        int linear = by * gridDim.x + bx;
        int xcd = linear & 7;
        int s = linear >> 3;
        bx = s & (gridDim.x - 1);
        by = xcd * (gridDim.y >> 3) + (s >> gxlog);
    }
    const int m0 = by << 7, n0 = bx << 7;
    const u16* Ab = A + (long long)blockIdx.z * a_zs + (long long)m0 * K;
    const u16* Bb = Bt + (long long)blockIdx.z * b_zs + (long long)n0 * K;

    // staging: unit u (16B) -> LDS slot u*16B; holds row m=u>>3, chunk pos p=u&7,
    // actual k-chunk c = p ^ (m&7). 4 issues of 256 units cover 128x64.
    long long ga[4];
    int lo[4];
#pragma unroll
    for (int i = 0; i < 4; ++i) {
        int u = tid + i * 256;
        int m = u >> 3, p = u & 7, c = p ^ (m & 7);
        ga[i] = (long long)m * K + c * 8;
        lo[i] = u * 8;  // u16 units
    }

    // compute-read offsets (u16 units): row m, k-chunk c0=ks*4+quad, pos=c0^(r&7)
    int aoff[4][2], boff[4][2];
#pragma unroll
    for (int t = 0; t < 4; ++t)
#pragma unroll
        for (int ks = 0; ks < 2; ++ks) {
            int m = wm + t * 16 + r;
            aoff[t][ks] = m * 64 + ((ks * 4 + quad) ^ (r & 7)) * 8;
            int n = wn + t * 16 + r;
            boff[t][ks] = n * 64 + ((ks * 4 + quad) ^ (r & 7)) * 8;
        }

    f32x4 acc[4][4];
#pragma unroll
    for (int i = 0; i < 4; ++i)
#pragma unroll
        for (int j = 0; j < 4; ++j) acc[i][j] = (f32x4){0.f, 0.f, 0.f, 0.f};

    for (int k0 = 0; k0 < K; k0 += 64) {
#pragma unroll
        for (int i = 0; i < 4; ++i)
            __builtin_amdgcn_global_load_lds((const __attribute__((address_space(1))) void*)(Ab + ga[i] + k0),
                                             (__attribute__((address_space(3))) void*)(As + lo[i]), 16, 0, 0);
#pragma unroll
        for (int i = 0; i < 4; ++i)
            __builtin_amdgcn_global_load_lds((const __attribute__((address_space(1))) void*)(Bb + ga[i] + k0),
                                             (__attribute__((address_space(3))) void*)(Bs + lo[i]), 16, 0, 0);
        __syncthreads();
#pragma unroll
        for (int ks = 0; ks < 2; ++ks) {
            bf16x8 af[4], bf[4];
#pragma unroll
            for (int t = 0; t < 4; ++t) af[t] = *(const bf16x8*)(As + aoff[t][ks]);
#pragma unroll
            for (int t = 0; t < 4; ++t) bf[t] = *(const bf16x8*)(Bs + boff[t][ks]);
#pragma unroll
            for (int i = 0; i < 4; ++i)
#pragma unroll
                for (int j = 0; j < 4; ++j)
                    acc[i][j] = __builtin_amdgcn_mfma_f32_16x16x32_bf16(bf[j], af[i], acc[i][j], 0, 0, 0);
        }
        __syncthreads();
    }

    // epilogue: lane (quad,r) of wave holds rows m0+wm+i*16+r, cols n0+wn+j*16+quad*4+e
    const long long zc = (long long)blockIdx.z * c_zs;
    float4 sh4[4], sc4[4];
    if (MODE != 3) {
#pragma unroll
        for (int j = 0; j < 4; ++j) {
            int colb = n0 + wn + j * 16 + quad * 4;
            sh4[j] = *(const float4*)&shift[colb];
            if (MODE == 1) sc4[j] = *(const float4*)&scale[colb];
        }
    }
#pragma unroll
    for (int i = 0; i < 4; ++i) {
        const int row = m0 + wm + i * 16 + r;
        float rsc = 0.f, rsh = 0.f;
        if (MODE == 3) { rsc = scale[row]; rsh = shift[row]; }
#pragma unroll
        for (int j = 0; j < 4; ++j) {
            const int colb = n0 + wn + j * 16 + quad * 4;
            f32x4 v = acc[i][j];
            if (MODE == 0) {
                uint2 o;
                o.x = pk2(v[0] + sh4[j].x, v[1] + sh4[j].y);
                o.y = pk2(v[2] + sh4[j].z, v[3] + sh4[j].w);
                *(uint2*)((u16*)Cv + zc + (long long)row * ldc + colb) = o;
            } else if (MODE == 1) {
                uint2 o;
                o.x = pk2(fmaxf(v[0] * sc4[j].x + sh4[j].x, 0.f), fmaxf(v[1] * sc4[j].y + sh4[j].y, 0.f));
                o.y = pk2(fmaxf(v[2] * sc4[j].z + sh4[j].z, 0.f), fmaxf(v[3] * sc4[j].w + sh4[j].w, 0.f));
                *(uint2*)((u16*)Cv + zc + (long long)row * ldc + colb) = o;
            } else if (MODE == 2) {
                float4 o = {v[0] + sh4[j].x, v[1] + sh4[j].y, v[2] + sh4[j].z, v[3] + sh4[j].w};
                *(float4*)((float*)Cv + zc + (long long)row * ldc + colb) = o;
            } else if (MODE == 3) {
                float4 o = {fmaxf(v[0] * rsc + rsh, 0.f), fmaxf(v[1] * rsc + rsh, 0.f),
                            fmaxf(v[2] * rsc + rsh, 0.f), fmaxf(v[3] * rsc + rsh, 0.f)};
                *(float4*)((float*)Cv + zc + (long long)row * ldc + colb) = o;
            } else {
                uint2 o;
                o.x = pk2(fmaxf(v[0] + sh4[j].x, 0.f), fmaxf(v[1] + sh4[j].y, 0.f));
                o.y = pk2(fmaxf(v[2] + sh4[j].z, 0.f), fmaxf(v[3] + sh4[j].w, 0.f));
                *(uint2*)((u16*)Cv + zc + (long long)row * ldc + colb) = o;
            }
        }
    }
}

// ================= weight prep =================
__device__ __attribute__((noinline)) void tconv(const float* src, u16* dst, int K, int N, int tk, int tn)
{
    __shared__ float t[32][33];
    const int tx = threadIdx.x & 31, ty = threadIdx.x >> 5;
#pragma unroll
    for (int i = 0; i < 4; ++i)
        t[ty + i * 8][tx] = src[(size_t)(tk * 32 + ty + i * 8) * N + tn * 32 + tx];
    __syncthreads();
#pragma unroll
    for (int i = 0; i < 4; ++i)
        dst[(size_t)(tn * 32 + ty + i * 8) * K + tk * 32 + tx] = f2b(t[tx][ty + i * 8]);
}

__device__ __attribute__((noinline)) void tconv_oa(const float* Woff, const float* Wattn, u16* dst, int tk, int tn)
{
    __shared__ float t[32][33];
    const int tx = threadIdx.x & 31, ty = threadIdx.x >> 5;
#pragma unroll
    for (int i = 0; i < 4; ++i) {
        int k = tk * 32 + ty + i * 8, n = tn * 32 + tx;
        float v = (n < 64) ? Woff[k * 64 + n] : ((n < 96) ? Wattn[k * 32 + n - 64] : 0.f);
        t[ty + i * 8][tx] = v;
    }
    __syncthreads();
#pragma unroll
    for (int i = 0; i < 4; ++i)
        dst[(size_t)(tn * 32 + ty + i * 8) * 256 + tk * 32 + tx] = f2b(t[tx][ty + i * 8]);
}

__global__ __launch_bounds__(256) void prep_weights(
    const float* __restrict__ Wval, const float* __restrict__ Wo,
    const float* __restrict__ W1, const float* __restrict__ W2,
    const float* __restrict__ Woff, const float* __restrict__ Wattn,
    const float* __restrict__ boff, const float* __restrict__ battn,
    const float* __restrict__ W_in, const float* __restrict__ W_out,
    const float* __restrict__ bn1g, const float* __restrict__ bn1b,
    const float* __restrict__ bn1m, const float* __restrict__ bn1v,
    const float* __restrict__ bn2g, const float* __restrict__ bn2b,
    const float* __restrict__ bn2m, const float* __restrict__ bn2v,
    u16* __restrict__ wvalT, u16* __restrict__ woT, u16* __restrict__ w1T,
    u16* __restrict__ w2T, u16* __restrict__ woaT,
    u16* __restrict__ winC, u16* __restrict__ woutC,
    float* __restrict__ bn1sc, float* __restrict__ bn1sh,
    float* __restrict__ bn2sc, float* __restrict__ bn2sh, float* __restrict__ boa)
{
    int bid = blockIdx.x;
    if (bid < 1344) {
        int l = bid / 672, r = bid % 672;
        if (r < 64) tconv(Wval + l * 65536, wvalT + l * 65536, 256, 256, r & 7, r >> 3);
        else if (r < 128) { r -= 64;  tconv(Wo + l * 65536, woT + l * 65536, 256, 256, r & 7, r >> 3); }
        else if (r < 384) { r -= 128; tconv(W1 + l * 262144, w1T + l * 262144, 256, 1024, r & 7, r >> 3); }
        else if (r < 640) { r -= 384; tconv(W2 + l * 262144, w2T + l * 262144, 1024, 256, r & 31, r >> 5); }
        else              { r -= 640; tconv_oa(Woff + l * 16384, Wattn + l * 8192, woaT + l * 32768, r & 7, r >> 3); }
    } else {
        int g = bid - 1344;
        int t = threadIdx.x;
        if (g < 32) {
            int base = g * 4096;
#pragma unroll
            for (int k = 0; k < 16; ++k) winC[base + k * 256 + t] = f2b(W_in[base + k * 256 + t]);
        } else if (g < 64) {
            int base = (g - 32) * 4096;
#pragma unroll
            for (int k = 0; k < 16; ++k) woutC[base + k * 256 + t] = f2b(W_out[base + k * 256 + t]);
        } else {
            { float s = bn1g[t] * rsqrtf(bn1v[t] + EPSV); bn1sc[t] = s; bn1sh[t] = bn1b[t] - bn1m[t] * s; }
            for (int c = 0; c < 2; ++c) {
                int i = c * 256 + t;
                float s = bn2g[i] * rsqrtf(bn2v[i] + EPSV);
                bn2sc[i] = s; bn2sh[i] = bn2b[i] - bn2m[i] * s;
            }
            if (t < 128)
                for (int l = 0; l < 2; ++l)
                    boa[l * 128 + t] = (t < 64) ? boff[l * 64 + t]
                                     : ((t < 96) ? battn[l * 32 + t - 64] : 0.f);
        }
    }
}

// ================= x (B,C,HW) -> xT (B,HW,C) bf16 =================
__global__ __launch_bounds__(256) void transpose_x(const float* __restrict__ x, u16* __restrict__ xT)
{
    __shared__ float t[64][65];
    const int b = blockIdx.z, p0 = blockIdx.y << 6, c0 = blockIdx.x << 6;
    const int tx = threadIdx.x & 63, ty = threadIdx.x >> 6;
    const float* xb = x + ((size_t)b * CINC + c0) * HWTOT + p0;
#pragma unroll
    for (int i = 0; i < 16; ++i)
        t[ty + i * 4][tx] = xb[(size_t)(ty + i * 4) * HWTOT + tx];
    __syncthreads();
    u16* xo = xT + ((size_t)b * HWTOT + p0) * CINC + c0;
#pragma unroll
    for (int i = 0; i < 16; ++i)
        xo[(size_t)(ty + i * 4) * CINC + tx] = f2b(t[tx][ty + i * 4]);
}

// ================= deformable sampling: 8 queries/block, 32 lanes/query =================
struct IW { int eo; float w; };

__global__ __launch_bounds__(256) void sample_kernel(
    const u16* __restrict__ val,      // (B*HW, D) bf16
    const float* __restrict__ oa,     // (B*HW, 128): [0..63]=off, [64..95]=attn logits
    u16* __restrict__ oms)            // (B*HW, D) bf16
{
    __shared__ float s_oa[8][96];
    __shared__ IW s_iw[8][32][5];
    const int t = threadIdx.x;
    const int bq0 = blockIdx.x << 3;
    const int b = blockIdx.x >> 9;

    {
        int qi = t >> 5, j = t & 31;
        if (j < 24)
            ((float4*)s_oa[qi])[j] = ((const float4*)oa)[((size_t)(bq0 + qi)) * 32 + j];
    }
    __syncthreads();

    {
        const int qi = t >> 5, hp = t & 31, h = hp >> 2, p = hp & 3;
        const float* so = s_oa[qi];
        float l0 = so[64 + h * 4 + 0], l1 = so[64 + h * 4 + 1];
        float l2 = so[64 + h * 4 + 2], l3 = so[64 + h * 4 + 3];
        float mx = fmaxf(fmaxf(l0, l1), fmaxf(l2, l3));
        float e0 = __expf(l0 - mx), e1 = __expf(l1 - mx), e2 = __expf(l2 - mx), e3 = __expf(l3 - mx);
        float inv = 1.0f / (e0 + e1 + e2 + e3);
        float aw = ((p == 0) ? e0 : (p == 1) ? e1 : (p == 2) ? e2 : e3) * inv;
        const int bq = bq0 + qi;
        float gx = (float)(bq & 63) + so[hp * 2 + 0];
        float gy = (float)((bq >> 6) & 63) + so[hp * 2 + 1];
        float x0f = floorf(gx), y0f = floorf(gy);
        float wx = gx - x0f, wy = gy - y0f;
        int x0 = (int)x0f, y0 = (int)y0f;
#pragma unroll
        for (int c = 0; c < 4; ++c) {
            int xi = x0 + (c & 1), yi = y0 + (c >> 1);
            bool ok = (xi >= 0) && (xi < 64) && (yi >= 0) && (yi < 64);
            float wgt = ((c & 1) ? wx : 1.0f - wx) * ((c >> 1) ? wy : 1.0f - wy);
            s_iw[qi][hp][c].eo = ok ? ((yi * 64 + xi) << 8) : 0;
            s_iw[qi][hp][c].w = ok ? aw * wgt : 0.f;
        }
    }
    __syncthreads();

    {
        const int qi = t >> 5, l = t & 31, h = l >> 2, cc = l & 3;
        const u16* base = val + ((size_t)b << 20) + (h << 5) + (cc << 3);
        float a[8] = {0.f, 0.f, 0.f, 0.f, 0.f, 0.f, 0.f, 0.f};
#pragma unroll
        for (int p = 0; p < 4; ++p)
#pragma unroll
            for (int c = 0; c < 4; ++c) {
                IW iw = s_iw[qi][(h << 2) + p][c];
                uint4 v = *(const uint4*)(base + iw.eo);
                a[0] += iw.w * blo(v.x); a[1] += iw.w * bhi(v.x);
                a[2] += iw.w * blo(v.y); a[3] += iw.w * bhi(v.y);
                a[4] += iw.w * blo(v.z); a[5] += iw.w * bhi(v.z);
                a[6] += iw.w * blo(v.w); a[7] += iw.w * bhi(v.w);
            }
        uint4 o;
        o.x = (uint32_t)f2b(a[0]) | ((uint32_t)f2b(a[1]) << 16);
        o.y = (uint32_t)f2b(a[2]) | ((uint32_t)f2b(a[3]) << 16);
        o.z = (uint32_t)f2b(a[4]) | ((uint32_t)f2b(a[5]) << 16);
        o.w = (uint32_t)f2b(a[6]) | ((uint32_t)f2b(a[7]) << 16);
        *(uint4*)(oms + (size_t)(bq0 + qi) * 256 + (h << 5) + (cc << 3)) = o;
    }
}

// ================= fused residual + LayerNorm; writes fp32 q and bf16 q16 =================
__global__ __launch_bounds__(256) void add_ln(
    float* __restrict__ q, u16* __restrict__ q16, const float* __restrict__ r,
    const float* __restrict__ g, const float* __restrict__ bta)
{
    const int row = blockIdx.x * 4 + (threadIdx.x >> 6);
    const int lane = threadIdx.x & 63;
    float4* qp = (float4*)(q + (size_t)row * DM);
    const float4* rp = (const float4*)(r + (size_t)row * DM);
    float4 a = qp[lane];
    float4 c = rp[lane];
    float x0 = a.x + c.x, x1 = a.y + c.y, x2 = a.z + c.z, x3 = a.w + c.w;
    float s = x0 + x1 + x2 + x3;
#pragma unroll
    for (int o = 32; o > 0; o >>= 1) s += __shfl_down(s, o);
    float mean = __shfl(s, 0) * (1.0f / 256.0f);
    float d0 = x0 - mean, d1 = x1 - mean, d2 = x2 - mean, d3 = x3 - mean;
    float vs = d0 * d0 + d1 * d1 + d2 * d2 + d3 * d3;
#pragma unroll
    for (int o = 32; o > 0; o >>= 1) vs += __shfl_down(vs, o);
    float rstd = rsqrtf(__shfl(vs, 0) * (1.0f / 256.0f) + EPSV);
    int base = lane * 4;
    float4 o4;
    o4.x = d0 * rstd * g[base + 0] + bta[base + 0];
    o4.y = d1 * rstd * g[base + 1] + bta[base + 1];
    o4.z = d2 * rstd * g[base + 2] + bta[base + 2];
    o4.w = d3 * rstd * g[base + 3] + bta[base + 3];
    qp[lane] = o4;
    ((uint2*)(q16 + (size_t)row * DM))[lane] = make_uint2(pk2(o4.x, o4.y), pk2(o4.z, o4.w));
}

__global__ __launch_bounds__(256) void bcast_q(
    const float4* __restrict__ qe, float4* __restrict__ q, u16* __restrict__ q16)
{
    const int i = blockIdx.x * 256 + threadIdx.x;
    float4 v = qe[i];
    uint2 pk = make_uint2(pk2(v.x, v.y), pk2(v.z, v.w));
#pragma unroll
    for (int b = 0; b < BBATCH; ++b) {
        q[(size_t)b * 262144 + i] = v;
        ((uint2*)q16)[(size_t)b * 262144 + i] = pk;
    }
}

extern "C" void kernel_launch(void* const* d_in, const int* in_sizes, int n_in,
                              void* d_out, int out_size, void* d_ws, size_t ws_size,
                              hipStream_t stream)
{
    (void)in_sizes; (void)n_in; (void)out_size; (void)ws_size;
    const float* x     = (const float*)d_in[0];
    const float* W_in  = (const float*)d_in[1];
    const float* bn1_g = (const float*)d_in[2];
    const float* bn1_b = (const float*)d_in[3];
    const float* bn1_m = (const float*)d_in[4];
    const float* bn1_v = (const float*)d_in[5];
    const float* qe    = (const float*)d_in[6];
    const float* Woff  = (const float*)d_in[7];
    const float* boff  = (const float*)d_in[8];
    const float* Wattn = (const float*)d_in[9];
    const float* battn = (const float*)d_in[10];
    const float* Wval  = (const float*)d_in[11];
    const float* bval  = (const float*)d_in[12];
    const float* Wo    = (const float*)d_in[13];
    const float* bo    = (const float*)d_in[14];
    const float* ln1_g = (const float*)d_in[15];
    const float* ln1_b = (const float*)d_in[16];
    const float* W1    = (const float*)d_in[17];
    const float* b1    = (const float*)d_in[18];
    const float* W2    = (const float*)d_in[19];
    const float* b2    = (const float*)d_in[20];
    const float* ln2_g = (const float*)d_in[21];
    const float* ln2_b = (const float*)d_in[22];
    const float* W_out = (const float*)d_in[23];
    const float* bn2_g = (const float*)d_in[24];
    const float* bn2_b = (const float*)d_in[25];
    const float* bn2_m = (const float*)d_in[26];
    const float* bn2_v = (const float*)d_in[27];
    float* out = (float*)d_out;

    char* w = (char*)d_ws;
    char* pool    = w;          w += 67108864;
    float* q      = (float*)w;  w += 33554432;
    float* resid  = (float*)w;  w += 33554432;
    u16*  q16     = (u16*)w;    w += 16777216;
    u16*  src16   = (u16*)w;    w += 16777216;
    u16*  wvalT   = (u16*)w;    w += 262144;
    u16*  woT     = (u16*)w;    w += 262144;
    u16*  w1T     = (u16*)w;    w += 1048576;
    u16*  w2T     = (u16*)w;    w += 1048576;
    u16*  woaT    = (u16*)w;    w += 131072;
    u16*  winC    = (u16*)w;    w += 262144;
    u16*  woutC   = (u16*)w;    w += 262144;
    float* bn1sc  = (float*)w;  w += 1024;
    float* bn1sh  = (float*)w;  w += 1024;
    float* bn2sc  = (float*)w;  w += 2048;
    float* bn2sh  = (float*)w;  w += 2048;
    float* boa    = (float*)w;  w += 1024;

    u16*  xT    = (u16*)pool;
    u16*  val16 = (u16*)pool;
    float* offat = (float*)(pool + 16777216);
    u16*  oms16 = (u16*)(pool + 33554432);
    u16*  hbuf16 = (u16*)pool;

    prep_weights<<<dim3(1409), 256, 0, stream>>>(
        Wval, Wo, W1, W2, Woff, Wattn, boff, battn, W_in, W_out,
        bn1_g, bn1_b, bn1_m, bn1_v, bn2_g, bn2_b, bn2_m, bn2_v,
        wvalT, woT, w1T, w2T, woaT, winC, woutC, bn1sc, bn1sh, bn2sc, bn2sh, boa);
    transpose_x<<<dim3(CINC / 64, HWTOT / 64, BBATCH), 256, 0, stream>>>(x, xT);
    bcast_q<<<dim3(1024), 256, 0, stream>>>((const float4*)qe, (float4*)q, q16);

    // proj_in: (32768,512)@(256,512)^T -> bf16 src
    mfma_gemm<1><<<dim3(2, 256, 1), 256, 0, stream>>>(
        xT, winC, bn1sc, bn1sh, src16, 32768, 256, 512, 256, 0, 0, 0, 1, 1);

    for (int l = 0; l < LYR; ++l) {
        mfma_gemm<0><<<dim3(2, 256, 1), 256, 0, stream>>>(
            src16, wvalT + l * 65536, nullptr, bval + l * 256, val16,
            32768, 256, 256, 256, 0, 0, 0, 1, 1);
        mfma_gemm<2><<<dim3(1, 256, 1), 256, 0, stream>>>(
            q16, woaT + l * 32768, nullptr, boa + l * 128, offat,
            32768, 128, 256, 128, 0, 0, 0, 1, 0);
        sample_kernel<<<dim3(4096), 256, 0, stream>>>(val16, offat, oms16);
        mfma_gemm<2><<<dim3(2, 256, 1), 256, 0, stream>>>(
            oms16, woT + l * 65536, nullptr, bo + l * 256, resid,
            32768, 256, 256, 256, 0, 0, 0, 1, 1);
        add_ln<<<dim3(8192), 256, 0, stream>>>(q, q16, resid, ln1_g + l * 256, ln1_b + l * 256);
        mfma_gemm<4><<<dim3(8, 256, 1), 256, 0, stream>>>(
            q16, w1T + l * 262144, nullptr, b1 + l * 1024, hbuf16,
            32768, 1024, 256, 1024, 0, 0, 0, 1, 3);
        mfma_gemm<2><<<dim3(2, 256, 1), 256, 0, stream>>>(
            hbuf16, w2T + l * 262144, nullptr, b2 + l * 256, resid,
            32768, 256, 1024, 256, 0, 0, 0, 1, 1);
        add_ln<<<dim3(8192), 256, 0, stream>>>(q, q16, resid, ln2_g + l * 256, ln2_b + l * 256);
    }

    // proj_out: per-batch (512,256)@(4096,256)^T -> fp32 out (B,C,HW)
    mfma_gemm<3><<<dim3(32, 4, BBATCH), 256, 0, stream>>>(
        woutC, q16, bn2sc, bn2sh, out, 512, 4096, 256, 4096,
        0, (long long)HWTOT * DM, (long long)CINC * HWTOT, 0, 0);
}

// Round 5
// 536.363 us; speedup vs baseline: 1.0518x; 1.0518x over previous
//
#include <hip/hip_runtime.h>
#include <cstdint>

#define LYR 2
#define DM  256
#define DFFN 1024
#define CINC 512
#define BBATCH 8
#define HWTOT 4096
#define EPSV 1e-5f

using u16 = unsigned short;
typedef __attribute__((ext_vector_type(8))) short bf16x8;
typedef __attribute__((ext_vector_type(4))) float f32x4;

__device__ inline u16 f2b(float v) {
    union { float f; uint32_t u; } x; x.f = v;
    uint32_t r = x.u + 0x7fffu + ((x.u >> 16) & 1u);
    return (u16)(r >> 16);
}
__device__ inline uint32_t pk2(float a, float b) {
    return (uint32_t)f2b(a) | ((uint32_t)f2b(b) << 16);
}
__device__ inline float blo(uint32_t d) {
    union { uint32_t i; float f; } x; x.i = d << 16; return x.f;
}
__device__ inline float bhi(uint32_t d) {
    union { uint32_t i; float f; } x; x.i = d & 0xffff0000u; return x.f;
}

// ============ bf16 MFMA GEMM: C = A(M,K) @ Bt(N,K)^T, 128x128 tile, BK=32 ============
// Swapped-operand mfma: lane holds 4 consecutive output COLUMNS -> packed stores.
// MODE 0: bf16 out, x+shift[col]                   (val)
// MODE 1: bf16 out, relu(x*scale[col]+shift[col])  (proj_in)
// MODE 2: fp32 out, x+shift[col]                   (offattn)
// MODE 3: fp32 out, relu(x*scale[row]+shift[row])  (proj_out)
// MODE 4: bf16 out, relu(x+shift[col])             (FFN1)
template<int MODE>
__global__ __launch_bounds__(256) void mfma_gemm(
    const u16* __restrict__ A, const u16* __restrict__ Bt,
    const float* __restrict__ scale, const float* __restrict__ shift,
    void* __restrict__ Cv, int M, int N, int K, int ldc,
    long long a_zs, long long b_zs, long long c_zs, int swz, int gxlog)
{
    __shared__ u16 As[4096];
    __shared__ u16 Bs[4096];
    const int tid = threadIdx.x;
    const int lane = tid & 63;
    const int wid = tid >> 6;
    const int wm = (wid & 1) << 6, wn = (wid >> 1) << 6;
    const int quad = lane >> 4, r = lane & 15;

    int bx = blockIdx.x, by = blockIdx.y;
    if (swz) {  // XCD-band swizzle: XCD k owns a contiguous band of row-tiles
        int linear = by * gridDim.x + bx;
        int xcd = linear & 7;
        int s = linear >> 3;
        bx = s & (gridDim.x - 1);
        by = xcd * (gridDim.y >> 3) + (s >> gxlog);
    }
    const int m0 = by << 7, n0 = bx << 7;
    const u16* Ab = A + (long long)blockIdx.z * a_zs + (long long)m0 * K;
    const u16* Bb = Bt + (long long)blockIdx.z * b_zs + (long long)n0 * K;

    // staging (BK=32): unit u (16B): row m=u>>2, pos p=u&3, chunk c=p^((m>>1)&3)
    const int u0 = tid, u1 = tid + 256;
    const int mu0 = u0 >> 2, cu0 = (u0 & 3) ^ ((mu0 >> 1) & 3);
    const int mu1 = u1 >> 2, cu1 = (u1 & 3) ^ ((mu1 >> 1) & 3);
    const long long ga0 = (long long)mu0 * K + cu0 * 8;
    const long long ga1 = (long long)mu1 * K + cu1 * 8;

    int aoff[4], boff[4];
#pragma unroll
    for (int t = 0; t < 4; ++t) {
        int m = wm + t * 16 + r;
        aoff[t] = (m * 4 + (quad ^ ((m >> 1) & 3))) * 8;
        int n = wn + t * 16 + r;
        boff[t] = (n * 4 + (quad ^ ((n >> 1) & 3))) * 8;
    }

    f32x4 acc[4][4];
#pragma unroll
    for (int i = 0; i < 4; ++i)
#pragma unroll
        for (int j = 0; j < 4; ++j) acc[i][j] = (f32x4){0.f, 0.f, 0.f, 0.f};

    for (int k0 = 0; k0 < K; k0 += 32) {
        __builtin_amdgcn_global_load_lds((const __attribute__((address_space(1))) void*)(Ab + ga0 + k0),
                                         (__attribute__((address_space(3))) void*)(As + u0 * 8), 16, 0, 0);
        __builtin_amdgcn_global_load_lds((const __attribute__((address_space(1))) void*)(Ab + ga1 + k0),
                                         (__attribute__((address_space(3))) void*)(As + u1 * 8), 16, 0, 0);
        __builtin_amdgcn_global_load_lds((const __attribute__((address_space(1))) void*)(Bb + ga0 + k0),
                                         (__attribute__((address_space(3))) void*)(Bs + u0 * 8), 16, 0, 0);
        __builtin_amdgcn_global_load_lds((const __attribute__((address_space(1))) void*)(Bb + ga1 + k0),
                                         (__attribute__((address_space(3))) void*)(Bs + u1 * 8), 16, 0, 0);
        __syncthreads();
        bf16x8 af[4], bf[4];
#pragma unroll
        for (int t = 0; t < 4; ++t) af[t] = *(const bf16x8*)(As + aoff[t]);
#pragma unroll
        for (int t = 0; t < 4; ++t) bf[t] = *(const bf16x8*)(Bs + boff[t]);
#pragma unroll
        for (int i = 0; i < 4; ++i)
#pragma unroll
            for (int j = 0; j < 4; ++j)
                acc[i][j] = __builtin_amdgcn_mfma_f32_16x16x32_bf16(bf[j], af[i], acc[i][j], 0, 0, 0);
        __syncthreads();
    }

    const long long zc = (long long)blockIdx.z * c_zs;
    float4 sh4[4], sc4[4];
    if (MODE != 3) {
#pragma unroll
        for (int j = 0; j < 4; ++j) {
            int colb = n0 + wn + j * 16 + quad * 4;
            sh4[j] = *(const float4*)&shift[colb];
            if (MODE == 1) sc4[j] = *(const float4*)&scale[colb];
        }
    }
#pragma unroll
    for (int i = 0; i < 4; ++i) {
        const int row = m0 + wm + i * 16 + r;
        float rsc = 0.f, rsh = 0.f;
        if (MODE == 3) { rsc = scale[row]; rsh = shift[row]; }
#pragma unroll
        for (int j = 0; j < 4; ++j) {
            const int colb = n0 + wn + j * 16 + quad * 4;
            f32x4 v = acc[i][j];
            if (MODE == 0) {
                uint2 o;
                o.x = pk2(v[0] + sh4[j].x, v[1] + sh4[j].y);
                o.y = pk2(v[2] + sh4[j].z, v[3] + sh4[j].w);
                *(uint2*)((u16*)Cv + zc + (long long)row * ldc + colb) = o;
            } else if (MODE == 1) {
                uint2 o;
                o.x = pk2(fmaxf(v[0] * sc4[j].x + sh4[j].x, 0.f), fmaxf(v[1] * sc4[j].y + sh4[j].y, 0.f));
                o.y = pk2(fmaxf(v[2] * sc4[j].z + sh4[j].z, 0.f), fmaxf(v[3] * sc4[j].w + sh4[j].w, 0.f));
                *(uint2*)((u16*)Cv + zc + (long long)row * ldc + colb) = o;
            } else if (MODE == 2) {
                float4 o = {v[0] + sh4[j].x, v[1] + sh4[j].y, v[2] + sh4[j].z, v[3] + sh4[j].w};
                *(float4*)((float*)Cv + zc + (long long)row * ldc + colb) = o;
            } else if (MODE == 3) {
                float4 o = {fmaxf(v[0] * rsc + rsh, 0.f), fmaxf(v[1] * rsc + rsh, 0.f),
                            fmaxf(v[2] * rsc + rsh, 0.f), fmaxf(v[3] * rsc + rsh, 0.f)};
                *(float4*)((float*)Cv + zc + (long long)row * ldc + colb) = o;
            } else {
                uint2 o;
                o.x = pk2(fmaxf(v[0] + sh4[j].x, 0.f), fmaxf(v[1] + sh4[j].y, 0.f));
                o.y = pk2(fmaxf(v[2] + sh4[j].z, 0.f), fmaxf(v[3] + sh4[j].w, 0.f));
                *(uint2*)((u16*)Cv + zc + (long long)row * ldc + colb) = o;
            }
        }
    }
}

// ============ GEMM (64 rows x full N=256) + bias + residual + LayerNorm fused ============
// C_row = LN(q[row] + A[row]@Bt^T + bias); writes q (fp32) and q16 (bf16) in place.
__global__ __launch_bounds__(256) void mfma_gemm_ln(
    const u16* __restrict__ A, const u16* __restrict__ Bt,
    const float* __restrict__ bias,
    float* __restrict__ q, u16* __restrict__ q16,
    const float* __restrict__ g, const float* __restrict__ beta, int K)
{
    __shared__ u16 As[2048];     // 64 rows x 32
    __shared__ u16 Bs[8192];     // 256 rows x 32
    __shared__ float red_s[4][64], red_ss[4][64];
    const int tid = threadIdx.x;
    const int lane = tid & 63;
    const int wid = tid >> 6;
    const int wn = wid << 6;
    const int quad = lane >> 4, r = lane & 15;
    const int m0 = blockIdx.x << 6;
    const u16* Ab = A + (long long)m0 * K;

    // A staging: 256 units (1/thread); B staging: 1024 units (4/thread)
    const int mA = tid >> 2, cA = (tid & 3) ^ ((mA >> 1) & 3);
    const long long gaA = (long long)mA * K + cA * 8;
    long long gaB[4];
    int loB[4];
#pragma unroll
    for (int i = 0; i < 4; ++i) {
        int u = tid + i * 256;
        int m = u >> 2, c = (u & 3) ^ ((m >> 1) & 3);
        gaB[i] = (long long)m * K + c * 8;
        loB[i] = u * 8;
    }

    int aoff[4], boff[4];
#pragma unroll
    for (int t = 0; t < 4; ++t) {
        int m = t * 16 + r;
        aoff[t] = (m * 4 + (quad ^ ((m >> 1) & 3))) * 8;
        int n = wn + t * 16 + r;
        boff[t] = (n * 4 + (quad ^ ((n >> 1) & 3))) * 8;
    }

    f32x4 acc[4][4];
#pragma unroll
    for (int i = 0; i < 4; ++i)
#pragma unroll
        for (int j = 0; j < 4; ++j) acc[i][j] = (f32x4){0.f, 0.f, 0.f, 0.f};

    for (int k0 = 0; k0 < K; k0 += 32) {
        __builtin_amdgcn_global_load_lds((const __attribute__((address_space(1))) void*)(Ab + gaA + k0),
                                         (__attribute__((address_space(3))) void*)(As + tid * 8), 16, 0, 0);
#pragma unroll
        for (int i = 0; i < 4; ++i)
            __builtin_amdgcn_global_load_lds((const __attribute__((address_space(1))) void*)(Bt + gaB[i] + k0),
                                             (__attribute__((address_space(3))) void*)(Bs + loB[i]), 16, 0, 0);
        __syncthreads();
        bf16x8 af[4], bf[4];
#pragma unroll
        for (int t = 0; t < 4; ++t) af[t] = *(const bf16x8*)(As + aoff[t]);
#pragma unroll
        for (int t = 0; t < 4; ++t) bf[t] = *(const bf16x8*)(Bs + boff[t]);
#pragma unroll
        for (int i = 0; i < 4; ++i)
#pragma unroll
            for (int j = 0; j < 4; ++j)
                acc[i][j] = __builtin_amdgcn_mfma_f32_16x16x32_bf16(bf[j], af[i], acc[i][j], 0, 0, 0);
        __syncthreads();
    }

    // epilogue: add bias + residual, then per-row LN over all 256 cols
    float4 sh4[4];
#pragma unroll
    for (int j = 0; j < 4; ++j)
        sh4[j] = *(const float4*)&bias[wn + j * 16 + quad * 4];

    float s_[4] = {0.f, 0.f, 0.f, 0.f}, ss_[4] = {0.f, 0.f, 0.f, 0.f};
#pragma unroll
    for (int i = 0; i < 4; ++i) {
        const int row = m0 + i * 16 + r;
#pragma unroll
        for (int j = 0; j < 4; ++j) {
            const int colb = wn + j * 16 + quad * 4;
            float4 qo = *(const float4*)&q[(size_t)row * DM + colb];
            acc[i][j][0] += sh4[j].x + qo.x;
            acc[i][j][1] += sh4[j].y + qo.y;
            acc[i][j][2] += sh4[j].z + qo.z;
            acc[i][j][3] += sh4[j].w + qo.w;
#pragma unroll
            for (int e = 0; e < 4; ++e) {
                s_[i] += acc[i][j][e];
                ss_[i] += acc[i][j][e] * acc[i][j][e];
            }
        }
    }
#pragma unroll
    for (int i = 0; i < 4; ++i) {
        s_[i] += __shfl_xor(s_[i], 16);  ss_[i] += __shfl_xor(ss_[i], 16);
        s_[i] += __shfl_xor(s_[i], 32);  ss_[i] += __shfl_xor(ss_[i], 32);
    }
    if (quad == 0) {
#pragma unroll
        for (int i = 0; i < 4; ++i) {
            red_s[wid][i * 16 + r] = s_[i];
            red_ss[wid][i * 16 + r] = ss_[i];
        }
    }
    __syncthreads();

    float mean[4], rstd[4];
#pragma unroll
    for (int i = 0; i < 4; ++i) {
        float S = 0.f, SS = 0.f;
#pragma unroll
        for (int w2 = 0; w2 < 4; ++w2) { S += red_s[w2][i * 16 + r]; SS += red_ss[w2][i * 16 + r]; }
        mean[i] = S * (1.0f / 256.0f);
        rstd[i] = rsqrtf(SS * (1.0f / 256.0f) - mean[i] * mean[i] + EPSV);
    }

    float4 g4[4], bt4[4];
#pragma unroll
    for (int j = 0; j < 4; ++j) {
        int colb = wn + j * 16 + quad * 4;
        g4[j] = *(const float4*)&g[colb];
        bt4[j] = *(const float4*)&beta[colb];
    }
#pragma unroll
    for (int i = 0; i < 4; ++i) {
        const int row = m0 + i * 16 + r;
#pragma unroll
        for (int j = 0; j < 4; ++j) {
            const int colb = wn + j * 16 + quad * 4;
            float o0 = (acc[i][j][0] - mean[i]) * rstd[i] * g4[j].x + bt4[j].x;
            float o1 = (acc[i][j][1] - mean[i]) * rstd[i] * g4[j].y + bt4[j].y;
            float o2 = (acc[i][j][2] - mean[i]) * rstd[i] * g4[j].z + bt4[j].z;
            float o3 = (acc[i][j][3] - mean[i]) * rstd[i] * g4[j].w + bt4[j].w;
            *(float4*)&q[(size_t)row * DM + colb] = make_float4(o0, o1, o2, o3);
            *(uint2*)(q16 + (size_t)row * DM + colb) = make_uint2(pk2(o0, o1), pk2(o2, o3));
        }
    }
}

// ================= weight prep =================
__device__ __attribute__((noinline)) void tconv(const float* src, u16* dst, int K, int N, int tk, int tn)
{
    __shared__ float t[32][33];
    const int tx = threadIdx.x & 31, ty = threadIdx.x >> 5;
#pragma unroll
    for (int i = 0; i < 4; ++i)
        t[ty + i * 8][tx] = src[(size_t)(tk * 32 + ty + i * 8) * N + tn * 32 + tx];
    __syncthreads();
#pragma unroll
    for (int i = 0; i < 4; ++i)
        dst[(size_t)(tn * 32 + ty + i * 8) * K + tk * 32 + tx] = f2b(t[tx][ty + i * 8]);
}

__device__ __attribute__((noinline)) void tconv_oa(const float* Woff, const float* Wattn, u16* dst, int tk, int tn)
{
    __shared__ float t[32][33];
    const int tx = threadIdx.x & 31, ty = threadIdx.x >> 5;
#pragma unroll
    for (int i = 0; i < 4; ++i) {
        int k = tk * 32 + ty + i * 8, n = tn * 32 + tx;
        float v = (n < 64) ? Woff[k * 64 + n] : ((n < 96) ? Wattn[k * 32 + n - 64] : 0.f);
        t[ty + i * 8][tx] = v;
    }
    __syncthreads();
#pragma unroll
    for (int i = 0; i < 4; ++i)
        dst[(size_t)(tn * 32 + ty + i * 8) * 256 + tk * 32 + tx] = f2b(t[tx][ty + i * 8]);
}

__global__ __launch_bounds__(256) void prep_weights(
    const float* __restrict__ Wval, const float* __restrict__ Wo,
    const float* __restrict__ W1, const float* __restrict__ W2,
    const float* __restrict__ Woff, const float* __restrict__ Wattn,
    const float* __restrict__ boff, const float* __restrict__ battn,
    const float* __restrict__ W_in, const float* __restrict__ W_out,
    const float* __restrict__ bn1g, const float* __restrict__ bn1b,
    const float* __restrict__ bn1m, const float* __restrict__ bn1v,
    const float* __restrict__ bn2g, const float* __restrict__ bn2b,
    const float* __restrict__ bn2m, const float* __restrict__ bn2v,
    u16* __restrict__ wvalT, u16* __restrict__ woT, u16* __restrict__ w1T,
    u16* __restrict__ w2T, u16* __restrict__ woaT,
    u16* __restrict__ winC, u16* __restrict__ woutC,
    float* __restrict__ bn1sc, float* __restrict__ bn1sh,
    float* __restrict__ bn2sc, float* __restrict__ bn2sh, float* __restrict__ boa)
{
    int bid = blockIdx.x;
    if (bid < 1344) {
        int l = bid / 672, r = bid % 672;
        if (r < 64) tconv(Wval + l * 65536, wvalT + l * 65536, 256, 256, r & 7, r >> 3);
        else if (r < 128) { r -= 64;  tconv(Wo + l * 65536, woT + l * 65536, 256, 256, r & 7, r >> 3); }
        else if (r < 384) { r -= 128; tconv(W1 + l * 262144, w1T + l * 262144, 256, 1024, r & 7, r >> 3); }
        else if (r < 640) { r -= 384; tconv(W2 + l * 262144, w2T + l * 262144, 1024, 256, r & 31, r >> 5); }
        else              { r -= 640; tconv_oa(Woff + l * 16384, Wattn + l * 8192, woaT + l * 32768, r & 7, r >> 3); }
    } else {
        int g = bid - 1344;
        int t = threadIdx.x;
        if (g < 32) {
            int base = g * 4096;
#pragma unroll
            for (int k = 0; k < 16; ++k) winC[base + k * 256 + t] = f2b(W_in[base + k * 256 + t]);
        } else if (g < 64) {
            int base = (g - 32) * 4096;
#pragma unroll
            for (int k = 0; k < 16; ++k) woutC[base + k * 256 + t] = f2b(W_out[base + k * 256 + t]);
        } else {
            { float s = bn1g[t] * rsqrtf(bn1v[t] + EPSV); bn1sc[t] = s; bn1sh[t] = bn1b[t] - bn1m[t] * s; }
            for (int c = 0; c < 2; ++c) {
                int i = c * 256 + t;
                float s = bn2g[i] * rsqrtf(bn2v[i] + EPSV);
                bn2sc[i] = s; bn2sh[i] = bn2b[i] - bn2m[i] * s;
            }
            if (t < 128)
                for (int l = 0; l < 2; ++l)
                    boa[l * 128 + t] = (t < 64) ? boff[l * 64 + t]
                                     : ((t < 96) ? battn[l * 32 + t - 64] : 0.f);
        }
    }
}

// ================= x (B,C,HW) -> xT (B,HW,C) bf16 =================
__global__ __launch_bounds__(256) void transpose_x(const float* __restrict__ x, u16* __restrict__ xT)
{
    __shared__ float t[64][65];
    const int b = blockIdx.z, p0 = blockIdx.y << 6, c0 = blockIdx.x << 6;
    const int tx = threadIdx.x & 63, ty = threadIdx.x >> 6;
    const float* xb = x + ((size_t)b * CINC + c0) * HWTOT + p0;
#pragma unroll
    for (int i = 0; i < 16; ++i)
        t[ty + i * 4][tx] = xb[(size_t)(ty + i * 4) * HWTOT + tx];
    __syncthreads();
    u16* xo = xT + ((size_t)b * HWTOT + p0) * CINC + c0;
#pragma unroll
    for (int i = 0; i < 16; ++i)
        xo[(size_t)(ty + i * 4) * CINC + tx] = f2b(t[tx][ty + i * 4]);
}

// ================= deformable sampling: 8 queries/block, 32 lanes/query =================
struct IW { int eo; float w; };

__global__ __launch_bounds__(256) void sample_kernel(
    const u16* __restrict__ val,      // (B*HW, D) bf16
    const float* __restrict__ oa,     // (B*HW, 128): [0..63]=off, [64..95]=attn logits
    u16* __restrict__ oms)            // (B*HW, D) bf16
{
    __shared__ float s_oa[8][96];
    __shared__ IW s_iw[8][32][5];
    const int t = threadIdx.x;
    const int bq0 = blockIdx.x << 3;
    const int b = blockIdx.x >> 9;

    {
        int qi = t >> 5, j = t & 31;
        if (j < 24)
            ((float4*)s_oa[qi])[j] = ((const float4*)oa)[((size_t)(bq0 + qi)) * 32 + j];
    }
    __syncthreads();

    {
        const int qi = t >> 5, hp = t & 31, h = hp >> 2, p = hp & 3;
        const float* so = s_oa[qi];
        float l0 = so[64 + h * 4 + 0], l1 = so[64 + h * 4 + 1];
        float l2 = so[64 + h * 4 + 2], l3 = so[64 + h * 4 + 3];
        float mx = fmaxf(fmaxf(l0, l1), fmaxf(l2, l3));
        float e0 = __expf(l0 - mx), e1 = __expf(l1 - mx), e2 = __expf(l2 - mx), e3 = __expf(l3 - mx);
        float inv = 1.0f / (e0 + e1 + e2 + e3);
        float aw = ((p == 0) ? e0 : (p == 1) ? e1 : (p == 2) ? e2 : e3) * inv;
        const int bq = bq0 + qi;
        float gx = (float)(bq & 63) + so[hp * 2 + 0];
        float gy = (float)((bq >> 6) & 63) + so[hp * 2 + 1];
        float x0f = floorf(gx), y0f = floorf(gy);
        float wx = gx - x0f, wy = gy - y0f;
        int x0 = (int)x0f, y0 = (int)y0f;
#pragma unroll
        for (int c = 0; c < 4; ++c) {
            int xi = x0 + (c & 1), yi = y0 + (c >> 1);
            bool ok = (xi >= 0) && (xi < 64) && (yi >= 0) && (yi < 64);
            float wgt = ((c & 1) ? wx : 1.0f - wx) * ((c >> 1) ? wy : 1.0f - wy);
            s_iw[qi][hp][c].eo = ok ? ((yi * 64 + xi) << 8) : 0;
            s_iw[qi][hp][c].w = ok ? aw * wgt : 0.f;
        }
    }
    __syncthreads();

    {
        const int qi = t >> 5, l = t & 31, h = l >> 2, cc = l & 3;
        const u16* base = val + ((size_t)b << 20) + (h << 5) + (cc << 3);
        float a[8] = {0.f, 0.f, 0.f, 0.f, 0.f, 0.f, 0.f, 0.f};
#pragma unroll
        for (int p = 0; p < 4; ++p)
#pragma unroll
            for (int c = 0; c < 4; ++c) {
                IW iw = s_iw[qi][(h << 2) + p][c];
                uint4 v = *(const uint4*)(base + iw.eo);
                a[0] += iw.w * blo(v.x); a[1] += iw.w * bhi(v.x);
                a[2] += iw.w * blo(v.y); a[3] += iw.w * bhi(v.y);
                a[4] += iw.w * blo(v.z); a[5] += iw.w * bhi(v.z);
                a[6] += iw.w * blo(v.w); a[7] += iw.w * bhi(v.w);
            }
        uint4 o;
        o.x = (uint32_t)f2b(a[0]) | ((uint32_t)f2b(a[1]) << 16);
        o.y = (uint32_t)f2b(a[2]) | ((uint32_t)f2b(a[3]) << 16);
        o.z = (uint32_t)f2b(a[4]) | ((uint32_t)f2b(a[5]) << 16);
        o.w = (uint32_t)f2b(a[6]) | ((uint32_t)f2b(a[7]) << 16);
        *(uint4*)(oms + (size_t)(bq0 + qi) * 256 + (h << 5) + (cc << 3)) = o;
    }
}

__global__ __launch_bounds__(256) void bcast_q(
    const float4* __restrict__ qe, float4* __restrict__ q, u16* __restrict__ q16)
{
    const int i = blockIdx.x * 256 + threadIdx.x;
    float4 v = qe[i];
    uint2 pk = make_uint2(pk2(v.x, v.y), pk2(v.z, v.w));
#pragma unroll
    for (int b = 0; b < BBATCH; ++b) {
        q[(size_t)b * 262144 + i] = v;
        ((uint2*)q16)[(size_t)b * 262144 + i] = pk;
    }
}

extern "C" void kernel_launch(void* const* d_in, const int* in_sizes, int n_in,
                              void* d_out, int out_size, void* d_ws, size_t ws_size,
                              hipStream_t stream)
{
    (void)in_sizes; (void)n_in; (void)out_size; (void)ws_size;
    const float* x     = (const float*)d_in[0];
    const float* W_in  = (const float*)d_in[1];
    const float* bn1_g = (const float*)d_in[2];
    const float* bn1_b = (const float*)d_in[3];
    const float* bn1_m = (const float*)d_in[4];
    const float* bn1_v = (const float*)d_in[5];
    const float* qe    = (const float*)d_in[6];
    const float* Woff  = (const float*)d_in[7];
    const float* boff  = (const float*)d_in[8];
    const float* Wattn = (const float*)d_in[9];
    const float* battn = (const float*)d_in[10];
    const float* Wval  = (const float*)d_in[11];
    const float* bval  = (const float*)d_in[12];
    const float* Wo    = (const float*)d_in[13];
    const float* bo    = (const float*)d_in[14];
    const float* ln1_g = (const float*)d_in[15];
    const float* ln1_b = (const float*)d_in[16];
    const float* W1    = (const float*)d_in[17];
    const float* b1    = (const float*)d_in[18];
    const float* W2    = (const float*)d_in[19];
    const float* b2    = (const float*)d_in[20];
    const float* ln2_g = (const float*)d_in[21];
    const float* ln2_b = (const float*)d_in[22];
    const float* W_out = (const float*)d_in[23];
    const float* bn2_g = (const float*)d_in[24];
    const float* bn2_b = (const float*)d_in[25];
    const float* bn2_m = (const float*)d_in[26];
    const float* bn2_v = (const float*)d_in[27];
    float* out = (float*)d_out;

    char* w = (char*)d_ws;
    // pool (time-disjoint): xT (33.5MB) | val16+offat+oms16 (50MB) | hbuf16 (67MB)
    char* pool    = w;          w += 67108864;
    float* q      = (float*)w;  w += 33554432;
    u16*  q16     = (u16*)w;    w += 16777216;
    u16*  src16   = (u16*)w;    w += 16777216;
    u16*  wvalT   = (u16*)w;    w += 262144;
    u16*  woT     = (u16*)w;    w += 262144;
    u16*  w1T     = (u16*)w;    w += 1048576;
    u16*  w2T     = (u16*)w;    w += 1048576;
    u16*  woaT    = (u16*)w;    w += 131072;
    u16*  winC    = (u16*)w;    w += 262144;
    u16*  woutC   = (u16*)w;    w += 262144;
    float* bn1sc  = (float*)w;  w += 1024;
    float* bn1sh  = (float*)w;  w += 1024;
    float* bn2sc  = (float*)w;  w += 2048;
    float* bn2sh  = (float*)w;  w += 2048;
    float* boa    = (float*)w;  w += 1024;

    u16*  xT     = (u16*)pool;
    u16*  val16  = (u16*)pool;
    float* offat = (float*)(pool + 16777216);
    u16*  oms16  = (u16*)(pool + 33554432);
    u16*  hbuf16 = (u16*)pool;

    prep_weights<<<dim3(1409), 256, 0, stream>>>(
        Wval, Wo, W1, W2, Woff, Wattn, boff, battn, W_in, W_out,
        bn1_g, bn1_b, bn1_m, bn1_v, bn2_g, bn2_b, bn2_m, bn2_v,
        wvalT, woT, w1T, w2T, woaT, winC, woutC, bn1sc, bn1sh, bn2sc, bn2sh, boa);
    transpose_x<<<dim3(CINC / 64, HWTOT / 64, BBATCH), 256, 0, stream>>>(x, xT);
    bcast_q<<<dim3(1024), 256, 0, stream>>>((const float4*)qe, (float4*)q, q16);

    // proj_in: (32768,512)@(256,512)^T -> bf16 src
    mfma_gemm<1><<<dim3(2, 256, 1), 256, 0, stream>>>(
        xT, winC, bn1sc, bn1sh, src16, 32768, 256, 512, 256, 0, 0, 0, 1, 1);

    for (int l = 0; l < LYR; ++l) {
        mfma_gemm<0><<<dim3(2, 256, 1), 256, 0, stream>>>(
            src16, wvalT + l * 65536, nullptr, bval + l * 256, val16,
            32768, 256, 256, 256, 0, 0, 0, 1, 1);
        mfma_gemm<2><<<dim3(1, 256, 1), 256, 0, stream>>>(
            q16, woaT + l * 32768, nullptr, boa + l * 128, offat,
            32768, 128, 256, 128, 0, 0, 0, 1, 0);
        sample_kernel<<<dim3(4096), 256, 0, stream>>>(val16, offat, oms16);
        // Wo GEMM + bias + residual + LN1 fused
        mfma_gemm_ln<<<dim3(512), 256, 0, stream>>>(
            oms16, woT + l * 65536, bo + l * 256, q, q16,
            ln1_g + l * 256, ln1_b + l * 256, 256);
        mfma_gemm<4><<<dim3(8, 256, 1), 256, 0, stream>>>(
            q16, w1T + l * 262144, nullptr, b1 + l * 1024, hbuf16,
            32768, 1024, 256, 1024, 0, 0, 0, 1, 3);
        // FFN2 GEMM + bias + residual + LN2 fused
        mfma_gemm_ln<<<dim3(512), 256, 0, stream>>>(
            hbuf16, w2T + l * 262144, b2 + l * 256, q, q16,
            ln2_g + l * 256, ln2_b + l * 256, 1024);
    }

    // proj_out: per-batch (512,256)@(4096,256)^T -> fp32 out (B,C,HW)
    mfma_gemm<3><<<dim3(32, 4, BBATCH), 256, 0, stream>>>(
        woutC, q16, bn2sc, bn2sh, out, 512, 4096, 256, 4096,
        0, (long long)HWTOT * DM, (long long)CINC * HWTOT, 0, 0);
}